// Round 12
// baseline (337.941 us; speedup 1.0000x reference)
//
#include <hip/hip_runtime.h>
#include <hip/hip_bf16.h>
#include <cstdint>
#include <cstddef>

#define NN 50000
#define NE 800000

using short8v = __attribute__((ext_vector_type(8))) short;
using f32x4 = __attribute__((ext_vector_type(4))) float;

__device__ __forceinline__ unsigned short f2bf(float f) {
    unsigned u = __float_as_uint(f);
    u += 0x7fffu + ((u >> 16) & 1u);
    return (unsigned short)(u >> 16);
}
__device__ __forceinline__ float bf2f(unsigned s) {
    return __uint_as_float(s << 16);
}

// ---------------- W pre-split: W1..W3 (128x128) + W4 (128x16) -> WT{h,l}[n][k] bf16 ----------------

__global__ __launch_bounds__(256) void wsplit(const float* __restrict__ Wa,
                                              const float* __restrict__ Wb,
                                              const float* __restrict__ Wc,
                                              const float* __restrict__ Wd,
                                              unsigned short* __restrict__ WTh,
                                              unsigned short* __restrict__ WTl) {
    int i = blockIdx.x * 256 + threadIdx.x;  // 0..51199
    float v;
    if (i < 49152) {
        int j = i >> 14;
        int idx = i & 16383;
        int n = idx >> 7, k = idx & 127;
        const float* W = (j == 0) ? Wa : (j == 1) ? Wb : Wc;
        v = W[k * 128 + n];
    } else {
        int idx = i - 49152;
        int n = idx >> 7, k = idx & 127;
        v = Wd[k * 16 + n];
    }
    unsigned short h = f2bf(v);
    WTh[i] = h;
    WTl[i] = f2bf(v - bf2f(h));
}

// ---------------- mega: layer-1 GEMM (raw h1) blocks + replicated degree-count blocks ----------------
// count: 4 replica counters per node, one per 64B line; rep = (e>>8)&3.
// Contention per line drops 16 -> ~4 serialized atomics.

__global__ __launch_bounds__(256) void mega(const float* __restrict__ Xf,
                                            const unsigned short* __restrict__ WTh,
                                            const unsigned short* __restrict__ WTl,
                                            float* __restrict__ out,
                                            const int* __restrict__ dst,
                                            int* __restrict__ cntR,
                                            int* __restrict__ rank,
                                            int N, int E, int gb) {
    __shared__ unsigned short xh[64 * 128];   // 16 KB, XOR-swizzled
    __shared__ unsigned short xl[64 * 128];   // 16 KB
    int tid = threadIdx.x;

    if ((int)blockIdx.x >= gb) {
        int ce = (int)blockIdx.x - gb;
        int e = ce * 256 + tid;
        if (e < E) {
            int d = dst[e];
            int rep = ce & 3;
            rank[e] = atomicAdd(&cntR[((d << 2) + rep) << 4], 1);
        }
        return;
    }

    int lane = tid & 63, wv = tid >> 6;
    int row0 = blockIdx.x * 64;

    #pragma unroll
    for (int i = 0; i < 4; ++i) {
        int id = i * 256 + tid;
        int r = id >> 4, kc = id & 15;
        uint4 vh = make_uint4(0, 0, 0, 0), vl = make_uint4(0, 0, 0, 0);
        if (row0 + r < N) {
            float4 a = *(const float4*)(Xf + (size_t)(row0 + r) * 128 + kc * 8);
            float4 b = *(const float4*)(Xf + (size_t)(row0 + r) * 128 + kc * 8 + 4);
            unsigned short h0 = f2bf(a.x), h1 = f2bf(a.y), h2 = f2bf(a.z), h3 = f2bf(a.w);
            unsigned short h4 = f2bf(b.x), h5 = f2bf(b.y), h6 = f2bf(b.z), h7 = f2bf(b.w);
            vh = make_uint4((unsigned)h0 | ((unsigned)h1 << 16),
                            (unsigned)h2 | ((unsigned)h3 << 16),
                            (unsigned)h4 | ((unsigned)h5 << 16),
                            (unsigned)h6 | ((unsigned)h7 << 16));
            vl = make_uint4((unsigned)f2bf(a.x - bf2f(h0)) | ((unsigned)f2bf(a.y - bf2f(h1)) << 16),
                            (unsigned)f2bf(a.z - bf2f(h2)) | ((unsigned)f2bf(a.w - bf2f(h3)) << 16),
                            (unsigned)f2bf(b.x - bf2f(h4)) | ((unsigned)f2bf(b.y - bf2f(h5)) << 16),
                            (unsigned)f2bf(b.z - bf2f(h6)) | ((unsigned)f2bf(b.w - bf2f(h7)) << 16));
        }
        int off = r * 128 + ((kc * 8) ^ ((r & 7) << 3));
        *(uint4*)&xh[off] = vh;
        *(uint4*)&xl[off] = vl;
    }
    __syncthreads();

    int mstrip = (wv & 1) * 32;
    int nbase = (wv >> 1) * 64;
    f32x4 acc[2][4] = {};

    for (int ks = 0; ks < 4; ++ks) {
        short8v afh[2], afl[2];
        #pragma unroll
        for (int mt = 0; mt < 2; ++mt) {
            int r = mstrip + mt * 16 + (lane & 15);
            int off = r * 128 + ((ks * 32 + ((lane >> 4) * 8)) ^ ((r & 7) << 3));
            afh[mt] = *(const short8v*)&xh[off];
            afl[mt] = *(const short8v*)&xl[off];
        }
        #pragma unroll
        for (int nt = 0; nt < 4; ++nt) {
            int c = nbase + nt * 16 + (lane & 15);
            size_t goff = (size_t)c * 128 + ks * 32 + (lane >> 4) * 8;
            short8v bfh = *(const short8v*)&WTh[goff];
            short8v bfl = *(const short8v*)&WTl[goff];
            #pragma unroll
            for (int mt = 0; mt < 2; ++mt) {
                acc[mt][nt] = __builtin_amdgcn_mfma_f32_16x16x32_bf16(afh[mt], bfh, acc[mt][nt], 0, 0, 0);
                acc[mt][nt] = __builtin_amdgcn_mfma_f32_16x16x32_bf16(afh[mt], bfl, acc[mt][nt], 0, 0, 0);
                acc[mt][nt] = __builtin_amdgcn_mfma_f32_16x16x32_bf16(afl[mt], bfh, acc[mt][nt], 0, 0, 0);
            }
        }
    }

    // C/D layout: col=lane&15, row=(lane>>4)*4+reg  [m89]
    #pragma unroll
    for (int mt = 0; mt < 2; ++mt) {
        #pragma unroll
        for (int i = 0; i < 4; ++i) {
            int r = row0 + mstrip + mt * 16 + (lane >> 4) * 4 + i;
            if (r < N) {
                #pragma unroll
                for (int nt = 0; nt < 4; ++nt) {
                    int cg = nbase + nt * 16 + (lane & 15);
                    out[(size_t)r * 128 + cg] = acc[mt][nt][i];
                }
            }
        }
    }
}

// ---------------- scans ----------------
// scan1: per node, sum 4 replica counters, emit per-replica base offsets + dinv,
// then block-level exclusive scan of totals.

__global__ __launch_bounds__(1024) void scan1(const int* __restrict__ cntR,
                                              int* __restrict__ roff,
                                              int* __restrict__ local,
                                              int* __restrict__ bsum,
                                              float* __restrict__ dinv, int N) {
    int t = threadIdx.x;
    int g = blockIdx.x * 1024 + t;
    int lane = t & 63, w = t >> 6;
    int v = 0;
    if (g < N) {
        int c0 = cntR[((g << 2) + 0) << 4];
        int c1 = cntR[((g << 2) + 1) << 4];
        int c2 = cntR[((g << 2) + 2) << 4];
        int c3 = cntR[((g << 2) + 3) << 4];
        int4 ro = make_int4(0, c0, c0 + c1, c0 + c1 + c2);
        *(int4*)&roff[g << 2] = ro;
        v = c0 + c1 + c2 + c3;
        dinv[g] = rsqrtf((float)v + 1.0f);
    }
    int x = v;
    #pragma unroll
    for (int off = 1; off < 64; off <<= 1) {
        int y = __shfl_up(x, off);
        if (lane >= off) x += y;
    }
    __shared__ int wsum[16];
    if (lane == 63) wsum[w] = x;
    __syncthreads();
    if (t < 16) {
        int s = wsum[t];
        int xx = s;
        #pragma unroll
        for (int off = 1; off < 16; off <<= 1) {
            int y = __shfl_up(xx, off);
            if (t >= off) xx += y;
        }
        wsum[t] = xx - s;
    }
    __syncthreads();
    int excl = wsum[w] + x - v;
    if (g < N) local[g] = excl;
    if (t == 1023) bsum[blockIdx.x] = excl + v;
}

__global__ __launch_bounds__(256) void scan3(const int* __restrict__ local,
                                             const int* __restrict__ bsum,
                                             int* __restrict__ rowptr,
                                             int N, int E, int NB) {
    __shared__ int sb[64];
    int t = threadIdx.x;
    if (t < 64) {
        int v = (t < NB) ? bsum[t] : 0;
        int x = v;
        #pragma unroll
        for (int off = 1; off < 64; off <<= 1) {
            int y = __shfl_up(x, off);
            if (t >= off) x += y;
        }
        sb[t] = x - v;
    }
    __syncthreads();
    int g = blockIdx.x * 256 + t;
    if (g < N) rowptr[g] = local[g] + sb[g >> 10];
    if (g == 0) rowptr[N] = E;
}

__global__ __launch_bounds__(256) void scatter_plain(const int* __restrict__ src,
                                                     const int* __restrict__ dst,
                                                     const int* __restrict__ rowptr,
                                                     const int* __restrict__ roff,
                                                     const int* __restrict__ rank,
                                                     int* __restrict__ csr, int E) {
    int e = blockIdx.x * 256 + threadIdx.x;
    if (e < E) {
        int d = dst[e];
        int rep = (e >> 8) & 3;
        csr[rowptr[d] + roff[(d << 2) + rep] + rank[e]] = src[e];
    }
}

// ---------------- bf16x3 MFMA GEMM (W2/W3): out = (X @ W) * dinv ----------------

__global__ __launch_bounds__(256) void gemm_w(const unsigned* __restrict__ Xh,
                                              const unsigned* __restrict__ Xl,
                                              const unsigned short* __restrict__ WTh,
                                              const unsigned short* __restrict__ WTl,
                                              const float* __restrict__ dinv,
                                              float* __restrict__ out, int N) {
    __shared__ unsigned short xh[64 * 128];
    __shared__ unsigned short xl[64 * 128];
    __shared__ unsigned short wh[128 * 40];
    __shared__ unsigned short wl[128 * 40];
    int tid = threadIdx.x;
    int lane = tid & 63, wv = tid >> 6;
    int row0 = blockIdx.x * 64;

    #pragma unroll
    for (int i = 0; i < 4; ++i) {
        int id = i * 256 + tid;
        int r = id >> 4, kc = id & 15;
        uint4 vh = make_uint4(0, 0, 0, 0), vl = make_uint4(0, 0, 0, 0);
        if (row0 + r < N) {
            vh = *(const uint4*)&Xh[(size_t)(row0 + r) * 64 + kc * 4];
            vl = *(const uint4*)&Xl[(size_t)(row0 + r) * 64 + kc * 4];
        }
        int off = r * 128 + ((kc * 8) ^ ((r & 7) << 3));
        *(uint4*)&xh[off] = vh;
        *(uint4*)&xl[off] = vl;
    }

    int mstrip = (wv & 1) * 32;
    int nbase = (wv >> 1) * 64;
    f32x4 acc[2][4] = {};

    for (int ks = 0; ks < 4; ++ks) {
        __syncthreads();
        #pragma unroll
        for (int i = 0; i < 2; ++i) {
            int id = i * 256 + tid;        // 0..511
            int n = id >> 2, q = id & 3;
            *(uint4*)&wh[n * 40 + q * 8] =
                *(const uint4*)&WTh[(size_t)n * 128 + ks * 32 + q * 8];
            *(uint4*)&wl[n * 40 + q * 8] =
                *(const uint4*)&WTl[(size_t)n * 128 + ks * 32 + q * 8];
        }
        __syncthreads();

        short8v afh[2], afl[2];
        #pragma unroll
        for (int mt = 0; mt < 2; ++mt) {
            int r = mstrip + mt * 16 + (lane & 15);
            int off = r * 128 + ((ks * 32 + ((lane >> 4) * 8)) ^ ((r & 7) << 3));
            afh[mt] = *(const short8v*)&xh[off];
            afl[mt] = *(const short8v*)&xl[off];
        }
        #pragma unroll
        for (int nt = 0; nt < 4; ++nt) {
            int c = nbase + nt * 16 + (lane & 15);
            int boff = c * 40 + (lane >> 4) * 8;
            short8v bfh = *(const short8v*)&wh[boff];
            short8v bfl = *(const short8v*)&wl[boff];
            #pragma unroll
            for (int mt = 0; mt < 2; ++mt) {
                acc[mt][nt] = __builtin_amdgcn_mfma_f32_16x16x32_bf16(afh[mt], bfh, acc[mt][nt], 0, 0, 0);
                acc[mt][nt] = __builtin_amdgcn_mfma_f32_16x16x32_bf16(afh[mt], bfl, acc[mt][nt], 0, 0, 0);
                acc[mt][nt] = __builtin_amdgcn_mfma_f32_16x16x32_bf16(afl[mt], bfh, acc[mt][nt], 0, 0, 0);
            }
        }
    }

    #pragma unroll
    for (int mt = 0; mt < 2; ++mt) {
        #pragma unroll
        for (int i = 0; i < 4; ++i) {
            int r = row0 + mstrip + mt * 16 + (lane >> 4) * 4 + i;
            if (r < N) {
                float dv = dinv[r];
                #pragma unroll
                for (int nt = 0; nt < 4; ++nt) {
                    int cg = nbase + nt * 16 + (lane & 15);
                    out[(size_t)r * 128 + cg] = acc[mt][nt][i] * dv;
                }
            }
        }
    }
}

// layer 4: X (bf16 hi/lo) @ W4 -> hs4 [N][16] fp32 scaled by dinv
__global__ __launch_bounds__(256) void gemm16(const unsigned* __restrict__ Xh,
                                              const unsigned* __restrict__ Xl,
                                              const float* __restrict__ W,
                                              const float* __restrict__ dinv,
                                              float* __restrict__ out, int N) {
    __shared__ float xs[64][128];
    __shared__ float ws4[128][16];
    int tid = threadIdx.x;
    int row0 = blockIdx.x * 64;

    #pragma unroll
    for (int i = 0; i < 2; ++i)
        ((float4*)ws4)[i * 256 + tid] = ((const float4*)W)[i * 256 + tid];

    #pragma unroll
    for (int i = 0; i < 8; ++i) {
        int id = i * 256 + tid;
        int r = id >> 5, c4 = id & 31;
        float4 v = make_float4(0.f, 0.f, 0.f, 0.f);
        if (row0 + r < N) {
            uint2 hh = *(const uint2*)&Xh[(size_t)(row0 + r) * 64 + c4 * 2];
            uint2 ll = *(const uint2*)&Xl[(size_t)(row0 + r) * 64 + c4 * 2];
            v.x = bf2f(hh.x & 0xffffu) + bf2f(ll.x & 0xffffu);
            v.y = bf2f(hh.x >> 16) + bf2f(ll.x >> 16);
            v.z = bf2f(hh.y & 0xffffu) + bf2f(ll.y & 0xffffu);
            v.w = bf2f(hh.y >> 16) + bf2f(ll.y >> 16);
        }
        *(float4*)&xs[r][c4 * 4] = v;
    }
    __syncthreads();

    int ty = tid >> 4, tx = tid & 15;
    float acc[4] = {};
    #pragma unroll 4
    for (int k = 0; k < 128; ++k) {
        float wvv = ws4[k][tx];
        #pragma unroll
        for (int i = 0; i < 4; ++i)
            acc[i] = fmaf(xs[ty * 4 + i][k], wvv, acc[i]);
    }
    #pragma unroll
    for (int i = 0; i < 4; ++i) {
        int r = row0 + ty * 4 + i;
        if (r < N) out[(size_t)r * 16 + tx] = acc[i] * dinv[r];
    }
}

// ---------------- plain aggregation (layers 2,3) ----------------

template <int ACT>
__global__ __launch_bounds__(256) void agg128(const float* __restrict__ HS,
                                              const int* __restrict__ rp,
                                              const int* __restrict__ csr,
                                              const float* __restrict__ dinv,
                                              const float* __restrict__ b,
                                              unsigned* __restrict__ Xh,
                                              unsigned* __restrict__ Xl, int N) {
    int wid = threadIdx.x >> 6, lane = threadIdx.x & 63;
    int n = blockIdx.x * 4 + wid;
    if (n >= N) return;
    const float2* H2 = (const float2*)HS;
    float2 a0 = H2[(size_t)n * 64 + lane];  // self term
    float2 a1 = make_float2(0.f, 0.f), a2 = a1, a3 = a1;
    float2 a4 = a1, a5 = a1, a6 = a1, a7 = a1;
    int e = rp[n], end = rp[n + 1];
    for (; e + 8 <= end; e += 8) {
        int s0 = csr[e], s1 = csr[e + 1], s2 = csr[e + 2], s3 = csr[e + 3];
        int s4 = csr[e + 4], s5 = csr[e + 5], s6 = csr[e + 6], s7 = csr[e + 7];
        float2 v0 = H2[(size_t)s0 * 64 + lane];
        float2 v1 = H2[(size_t)s1 * 64 + lane];
        float2 v2 = H2[(size_t)s2 * 64 + lane];
        float2 v3 = H2[(size_t)s3 * 64 + lane];
        float2 v4 = H2[(size_t)s4 * 64 + lane];
        float2 v5 = H2[(size_t)s5 * 64 + lane];
        float2 v6 = H2[(size_t)s6 * 64 + lane];
        float2 v7 = H2[(size_t)s7 * 64 + lane];
        a0.x += v0.x; a0.y += v0.y; a1.x += v1.x; a1.y += v1.y;
        a2.x += v2.x; a2.y += v2.y; a3.x += v3.x; a3.y += v3.y;
        a4.x += v4.x; a4.y += v4.y; a5.x += v5.x; a5.y += v5.y;
        a6.x += v6.x; a6.y += v6.y; a7.x += v7.x; a7.y += v7.y;
    }
    if (e + 4 <= end) {
        int s0 = csr[e], s1 = csr[e + 1], s2 = csr[e + 2], s3 = csr[e + 3];
        float2 v0 = H2[(size_t)s0 * 64 + lane];
        float2 v1 = H2[(size_t)s1 * 64 + lane];
        float2 v2 = H2[(size_t)s2 * 64 + lane];
        float2 v3 = H2[(size_t)s3 * 64 + lane];
        a4.x += v0.x; a4.y += v0.y; a5.x += v1.x; a5.y += v1.y;
        a6.x += v2.x; a6.y += v2.y; a7.x += v3.x; a7.y += v3.y;
        e += 4;
    }
    for (; e < end; ++e) {
        int s = csr[e];
        float2 v = H2[(size_t)s * 64 + lane];
        a0.x += v.x; a0.y += v.y;
    }
    float accx = ((a0.x + a1.x) + (a2.x + a3.x)) + ((a4.x + a5.x) + (a6.x + a7.x));
    float accy = ((a0.y + a1.y) + (a2.y + a3.y)) + ((a4.y + a5.y) + (a6.y + a7.y));
    float dv = dinv[n];
    float2 bb = ((const float2*)b)[lane];
    float ox = fmaf(dv, accx, bb.x);
    float oy = fmaf(dv, accy, bb.y);
    if (ACT == 1) { ox = tanhf(ox); oy = tanhf(oy); }
    else if (ACT == 2) {
        ox = ox > 0.f ? ox : 0.01f * ox;
        oy = oy > 0.f ? oy : 0.01f * oy;
    }
    unsigned short h0 = f2bf(ox), h1 = f2bf(oy);
    float l0 = ox - bf2f(h0), l1 = oy - bf2f(h1);
    Xh[(size_t)n * 64 + lane] = (unsigned)h0 | ((unsigned)h1 << 16);
    Xl[(size_t)n * 64 + lane] = (unsigned)f2bf(l0) | ((unsigned)f2bf(l1) << 16);
}

// ---------------- layer-1 aggregation (standalone, deferred dinv) ----------------

__global__ __launch_bounds__(256) void agg_defer(const float* __restrict__ HS,
                                                 const int* __restrict__ rp,
                                                 const int* __restrict__ csr,
                                                 const float* __restrict__ dinv,
                                                 const float* __restrict__ b,
                                                 unsigned* __restrict__ Xh,
                                                 unsigned* __restrict__ Xl, int N) {
    int wid = threadIdx.x >> 6, lane = threadIdx.x & 63;
    int n = blockIdx.x * 4 + wid;
    if (n >= N) return;
    const float2* H2 = (const float2*)HS;
    float2 self = H2[(size_t)n * 64 + lane];
    float2 a0 = make_float2(0.f, 0.f), a1 = a0, a2 = a0, a3 = a0;
    float2 a4 = a0, a5 = a0, a6 = a0, a7 = a0;
    int e = rp[n], end = rp[n + 1];
    for (; e + 8 <= end; e += 8) {
        int s0 = csr[e], s1 = csr[e + 1], s2 = csr[e + 2], s3 = csr[e + 3];
        int s4 = csr[e + 4], s5 = csr[e + 5], s6 = csr[e + 6], s7 = csr[e + 7];
        float2 v0 = H2[(size_t)s0 * 64 + lane];
        float2 v1 = H2[(size_t)s1 * 64 + lane];
        float2 v2 = H2[(size_t)s2 * 64 + lane];
        float2 v3 = H2[(size_t)s3 * 64 + lane];
        float2 v4 = H2[(size_t)s4 * 64 + lane];
        float2 v5 = H2[(size_t)s5 * 64 + lane];
        float2 v6 = H2[(size_t)s6 * 64 + lane];
        float2 v7 = H2[(size_t)s7 * 64 + lane];
        float d0 = dinv[s0], d1 = dinv[s1], d2 = dinv[s2], d3 = dinv[s3];
        float d4 = dinv[s4], d5 = dinv[s5], d6 = dinv[s6], d7 = dinv[s7];
        a0.x = fmaf(v0.x, d0, a0.x); a0.y = fmaf(v0.y, d0, a0.y);
        a1.x = fmaf(v1.x, d1, a1.x); a1.y = fmaf(v1.y, d1, a1.y);
        a2.x = fmaf(v2.x, d2, a2.x); a2.y = fmaf(v2.y, d2, a2.y);
        a3.x = fmaf(v3.x, d3, a3.x); a3.y = fmaf(v3.y, d3, a3.y);
        a4.x = fmaf(v4.x, d4, a4.x); a4.y = fmaf(v4.y, d4, a4.y);
        a5.x = fmaf(v5.x, d5, a5.x); a5.y = fmaf(v5.y, d5, a5.y);
        a6.x = fmaf(v6.x, d6, a6.x); a6.y = fmaf(v6.y, d6, a6.y);
        a7.x = fmaf(v7.x, d7, a7.x); a7.y = fmaf(v7.y, d7, a7.y);
    }
    if (e + 4 <= end) {
        int s0 = csr[e], s1 = csr[e + 1], s2 = csr[e + 2], s3 = csr[e + 3];
        float2 v0 = H2[(size_t)s0 * 64 + lane];
        float2 v1 = H2[(size_t)s1 * 64 + lane];
        float2 v2 = H2[(size_t)s2 * 64 + lane];
        float2 v3 = H2[(size_t)s3 * 64 + lane];
        float d0 = dinv[s0], d1 = dinv[s1], d2 = dinv[s2], d3 = dinv[s3];
        a4.x = fmaf(v0.x, d0, a4.x); a4.y = fmaf(v0.y, d0, a4.y);
        a5.x = fmaf(v1.x, d1, a5.x); a5.y = fmaf(v1.y, d1, a5.y);
        a6.x = fmaf(v2.x, d2, a6.x); a6.y = fmaf(v2.y, d2, a6.y);
        a7.x = fmaf(v3.x, d3, a7.x); a7.y = fmaf(v3.y, d3, a7.y);
        e += 4;
    }
    for (; e < end; ++e) {
        int s = csr[e];
        float2 v = H2[(size_t)s * 64 + lane];
        float d = dinv[s];
        a0.x = fmaf(v.x, d, a0.x); a0.y = fmaf(v.y, d, a0.y);
    }
    float accx = ((a0.x + a1.x) + (a2.x + a3.x)) + ((a4.x + a5.x) + (a6.x + a7.x));
    float accy = ((a0.y + a1.y) + (a2.y + a3.y)) + ((a4.y + a5.y) + (a6.y + a7.y));
    float dv = dinv[n];
    accx = fmaf(dv, self.x, accx);
    accy = fmaf(dv, self.y, accy);
    float2 bb = ((const float2*)b)[lane];
    float ox = fmaf(dv, accx, bb.x);
    float oy = fmaf(dv, accy, bb.y);
    unsigned short h0 = f2bf(ox), h1 = f2bf(oy);
    float l0 = ox - bf2f(h0), l1 = oy - bf2f(h1);
    Xh[(size_t)n * 64 + lane] = (unsigned)h0 | ((unsigned)h1 << 16);
    Xl[(size_t)n * 64 + lane] = (unsigned)f2bf(l0) | ((unsigned)f2bf(l1) << 16);
}

// ---------------- layer-4 aggregation + classifier head ----------------

__global__ __launch_bounds__(256) void final_layer(const float* __restrict__ HS4,
                                                   const int* __restrict__ rp,
                                                   const int* __restrict__ csr,
                                                   const float* __restrict__ dinv,
                                                   const float* __restrict__ b4,
                                                   const float* __restrict__ Wc,
                                                   const float* __restrict__ bc,
                                                   float* __restrict__ out, int N) {
    int wid = threadIdx.x >> 6, lane = threadIdx.x & 63;
    int n = blockIdx.x * 4 + wid;
    if (n >= N) return;
    int f = lane & 15, g = lane >> 4;
    float acc = 0.f;
    int beg = rp[n], end = rp[n + 1];
    for (int e = beg + g; e < end; e += 4)
        acc += HS4[(size_t)csr[e] * 16 + f];
    acc += __shfl_xor(acc, 16);
    acc += __shfl_xor(acc, 32);
    acc += HS4[(size_t)n * 16 + f];
    float t = fmaf(dinv[n], acc, b4[f]);
    t = t > 0.f ? t : 0.01f * t;
    float p = t * Wc[f];
    p += __shfl_xor(p, 1);
    p += __shfl_xor(p, 2);
    p += __shfl_xor(p, 4);
    p += __shfl_xor(p, 8);
    if (lane == 0) {
        float z = p + bc[0];
        out[n] = z > 0.f ? z : expm1f(z);
    }
}

// ---------------- launch ----------------

extern "C" void kernel_launch(void* const* d_in, const int* in_sizes, int n_in,
                              void* d_out, int out_size, void* d_ws, size_t ws_size,
                              hipStream_t stream) {
    const int N = NN, E = NE;
    const float* x  = (const float*)d_in[0];
    const int*   ei = (const int*)d_in[1];
    const float* W1 = (const float*)d_in[2];
    const float* b1 = (const float*)d_in[3];
    const float* W2 = (const float*)d_in[4];
    const float* b2 = (const float*)d_in[5];
    const float* W3 = (const float*)d_in[6];
    const float* b3 = (const float*)d_in[7];
    const float* W4 = (const float*)d_in[8];
    const float* b4 = (const float*)d_in[9];
    const float* Wc = (const float*)d_in[10];
    const float* bc = (const float*)d_in[11];
    float* out = (float*)d_out;
    const int* src = ei;
    const int* dst = ei + E;

    char* p = (char*)d_ws;
    auto carve = [&](size_t bytes) -> char* {
        char* q = p;
        p += (bytes + 255) & ~(size_t)255;
        return q;
    };
    int*            cntR   = (int*)carve((size_t)N * 4 * 16 * 4);   // 12.8 MB, 4 replicas x 64B
    int*            roff   = (int*)carve((size_t)N * 4 * 4);        // per-replica base offsets
    int*            rank   = (int*)carve((size_t)E * 4);
    int*            rowptr = (int*)carve((size_t)(N + 1) * 4);
    float*          dinv   = (float*)carve((size_t)N * 4);
    int*            csr    = (int*)carve((size_t)E * 4);
    int*            locsc  = (int*)carve((size_t)N * 4);
    int*            bsum   = (int*)carve((size_t)64 * 4);
    unsigned short* WTh    = (unsigned short*)carve((size_t)(3 * 16384 + 2048) * 2);
    unsigned short* WTl    = (unsigned short*)carve((size_t)(3 * 16384 + 2048) * 2);
    unsigned*       Xh     = (unsigned*)carve((size_t)N * 64 * 4);
    unsigned*       Xl     = (unsigned*)carve((size_t)N * 64 * 4);
    float*          bufB   = (float*)carve((size_t)N * 128 * 4);
    float*          hs4    = (float*)carve((size_t)N * 16 * 4);

    const int NB = (N + 1023) / 1024;              // 49
    const int gblocks = (N + 63) / 64;             // 782
    const int cblocks = (E + 255) / 256;           // 3125
    const int wblocks = (3 * 16384 + 2048) / 256;  // 200
    const int ablocks = (N + 3) / 4;               // 12500

    hipMemsetAsync(cntR, 0, (size_t)N * 4 * 16 * 4, stream);
    wsplit<<<wblocks, 256, 0, stream>>>(W1, W2, W3, W4, WTh, WTl);
    // concurrent: layer-1 GEMM (raw h1) + replicated degree count
    mega<<<gblocks + cblocks, 256, 0, stream>>>(x, WTh, WTl, bufB, dst, cntR, rank, N, E, gblocks);
    scan1<<<NB, 1024, 0, stream>>>(cntR, roff, locsc, bsum, dinv, N);
    scan3<<<(N + 255) / 256, 256, 0, stream>>>(locsc, bsum, rowptr, N, E, NB);
    scatter_plain<<<cblocks, 256, 0, stream>>>(src, dst, rowptr, roff, rank, csr, E);

    // layer 1 agg (deferred dinv) -> split
    agg_defer<<<ablocks, 256, 0, stream>>>(bufB, rowptr, csr, dinv, b1, Xh, Xl, N);
    // layer 2
    gemm_w<<<gblocks, 256, 0, stream>>>(Xh, Xl, WTh + 16384, WTl + 16384, dinv, bufB, N);
    agg128<1><<<ablocks, 256, 0, stream>>>(bufB, rowptr, csr, dinv, b2, Xh, Xl, N);
    // layer 3
    gemm_w<<<gblocks, 256, 0, stream>>>(Xh, Xl, WTh + 32768, WTl + 32768, dinv, bufB, N);
    agg128<2><<<ablocks, 256, 0, stream>>>(bufB, rowptr, csr, dinv, b3, Xh, Xl, N);
    // layer 4 + head
    gemm16<<<gblocks, 256, 0, stream>>>(Xh, Xl, W4, dinv, hs4, N);
    final_layer<<<ablocks, 256, 0, stream>>>(hs4, rowptr, csr, dinv, b4, Wc, bc, out, N);
}

// Round 13
// 329.498 us; speedup vs baseline: 1.0256x; 1.0256x over previous
//
#include <hip/hip_runtime.h>
#include <hip/hip_bf16.h>
#include <cstdint>
#include <cstddef>

#define NN 50000
#define NE 800000

using short8v = __attribute__((ext_vector_type(8))) short;
using f32x4 = __attribute__((ext_vector_type(4))) float;

__device__ __forceinline__ unsigned short f2bf(float f) {
    unsigned u = __float_as_uint(f);
    u += 0x7fffu + ((u >> 16) & 1u);
    return (unsigned short)(u >> 16);
}
__device__ __forceinline__ float bf2f(unsigned s) {
    return __uint_as_float(s << 16);
}

// ---------------- W pre-split (+ counter zeroing packed as tail blocks) ----------------
// blocks [0, wb): W1..W3 (128x128) + W4 (128x16) -> WT{h,l}[n][k] bf16.
// blocks [wb, wb+3125): zero cntP (3.2 MB). Independent work; ordered vs mega by kernel boundary.

__global__ __launch_bounds__(256) void wsplit_zero(const float* __restrict__ Wa,
                                                   const float* __restrict__ Wb,
                                                   const float* __restrict__ Wc,
                                                   const float* __restrict__ Wd,
                                                   unsigned short* __restrict__ WTh,
                                                   unsigned short* __restrict__ WTl,
                                                   int* __restrict__ cntP, int wb) {
    if ((int)blockIdx.x >= wb) {
        int i = ((int)blockIdx.x - wb) * 256 + threadIdx.x;
        if (i < NN * 16) cntP[i] = 0;
        return;
    }
    int i = blockIdx.x * 256 + threadIdx.x;  // 0..51199
    float v;
    if (i < 49152) {
        int j = i >> 14;
        int idx = i & 16383;
        int n = idx >> 7, k = idx & 127;
        const float* W = (j == 0) ? Wa : (j == 1) ? Wb : Wc;
        v = W[k * 128 + n];
    } else {
        int idx = i - 49152;
        int n = idx >> 7, k = idx & 127;
        v = Wd[k * 16 + n];
    }
    unsigned short h = f2bf(v);
    WTh[i] = h;
    WTl[i] = f2bf(v - bf2f(h));
}

// ---------------- mega: layer-1 GEMM (raw h1, no dinv) blocks + degree-count blocks ----------------

__global__ __launch_bounds__(256) void mega(const float* __restrict__ Xf,
                                            const unsigned short* __restrict__ WTh,
                                            const unsigned short* __restrict__ WTl,
                                            float* __restrict__ out,
                                            const int* __restrict__ dst,
                                            int* __restrict__ cntP,
                                            int* __restrict__ rank,
                                            int N, int E, int gb) {
    __shared__ unsigned short xh[64 * 128];   // 16 KB, XOR-swizzled
    __shared__ unsigned short xl[64 * 128];   // 16 KB
    int tid = threadIdx.x;

    if ((int)blockIdx.x >= gb) {
        int e = ((int)blockIdx.x - gb) * 256 + tid;
        if (e < E) {
            int d = dst[e];
            rank[e] = atomicAdd(&cntP[d << 4], 1);
        }
        return;
    }

    int lane = tid & 63, wv = tid >> 6;
    int row0 = blockIdx.x * 64;

    #pragma unroll
    for (int i = 0; i < 4; ++i) {
        int id = i * 256 + tid;
        int r = id >> 4, kc = id & 15;
        uint4 vh = make_uint4(0, 0, 0, 0), vl = make_uint4(0, 0, 0, 0);
        if (row0 + r < N) {
            float4 a = *(const float4*)(Xf + (size_t)(row0 + r) * 128 + kc * 8);
            float4 b = *(const float4*)(Xf + (size_t)(row0 + r) * 128 + kc * 8 + 4);
            unsigned short h0 = f2bf(a.x), h1 = f2bf(a.y), h2 = f2bf(a.z), h3 = f2bf(a.w);
            unsigned short h4 = f2bf(b.x), h5 = f2bf(b.y), h6 = f2bf(b.z), h7 = f2bf(b.w);
            vh = make_uint4((unsigned)h0 | ((unsigned)h1 << 16),
                            (unsigned)h2 | ((unsigned)h3 << 16),
                            (unsigned)h4 | ((unsigned)h5 << 16),
                            (unsigned)h6 | ((unsigned)h7 << 16));
            vl = make_uint4((unsigned)f2bf(a.x - bf2f(h0)) | ((unsigned)f2bf(a.y - bf2f(h1)) << 16),
                            (unsigned)f2bf(a.z - bf2f(h2)) | ((unsigned)f2bf(a.w - bf2f(h3)) << 16),
                            (unsigned)f2bf(b.x - bf2f(h4)) | ((unsigned)f2bf(b.y - bf2f(h5)) << 16),
                            (unsigned)f2bf(b.z - bf2f(h6)) | ((unsigned)f2bf(b.w - bf2f(h7)) << 16));
        }
        int off = r * 128 + ((kc * 8) ^ ((r & 7) << 3));
        *(uint4*)&xh[off] = vh;
        *(uint4*)&xl[off] = vl;
    }
    __syncthreads();

    int mstrip = (wv & 1) * 32;
    int nbase = (wv >> 1) * 64;
    f32x4 acc[2][4] = {};

    for (int ks = 0; ks < 4; ++ks) {
        short8v afh[2], afl[2];
        #pragma unroll
        for (int mt = 0; mt < 2; ++mt) {
            int r = mstrip + mt * 16 + (lane & 15);
            int off = r * 128 + ((ks * 32 + ((lane >> 4) * 8)) ^ ((r & 7) << 3));
            afh[mt] = *(const short8v*)&xh[off];
            afl[mt] = *(const short8v*)&xl[off];
        }
        #pragma unroll
        for (int nt = 0; nt < 4; ++nt) {
            int c = nbase + nt * 16 + (lane & 15);
            size_t goff = (size_t)c * 128 + ks * 32 + (lane >> 4) * 8;
            short8v bfh = *(const short8v*)&WTh[goff];
            short8v bfl = *(const short8v*)&WTl[goff];
            #pragma unroll
            for (int mt = 0; mt < 2; ++mt) {
                acc[mt][nt] = __builtin_amdgcn_mfma_f32_16x16x32_bf16(afh[mt], bfh, acc[mt][nt], 0, 0, 0);
                acc[mt][nt] = __builtin_amdgcn_mfma_f32_16x16x32_bf16(afh[mt], bfl, acc[mt][nt], 0, 0, 0);
                acc[mt][nt] = __builtin_amdgcn_mfma_f32_16x16x32_bf16(afl[mt], bfh, acc[mt][nt], 0, 0, 0);
            }
        }
    }

    // C/D layout: col=lane&15, row=(lane>>4)*4+reg  [m89]
    #pragma unroll
    for (int mt = 0; mt < 2; ++mt) {
        #pragma unroll
        for (int i = 0; i < 4; ++i) {
            int r = row0 + mstrip + mt * 16 + (lane >> 4) * 4 + i;
            if (r < N) {
                #pragma unroll
                for (int nt = 0; nt < 4; ++nt) {
                    int cg = nbase + nt * 16 + (lane & 15);
                    out[(size_t)r * 128 + cg] = acc[mt][nt][i];
                }
            }
        }
    }
}

// ---------------- scans ----------------

__global__ __launch_bounds__(1024) void scan1(const int* __restrict__ cntP,
                                              int* __restrict__ local,
                                              int* __restrict__ bsum,
                                              float* __restrict__ dinv, int N) {
    int t = threadIdx.x;
    int g = blockIdx.x * 1024 + t;
    int lane = t & 63, w = t >> 6;
    int v = (g < N) ? cntP[g << 4] : 0;
    if (g < N) dinv[g] = rsqrtf((float)v + 1.0f);
    int x = v;
    #pragma unroll
    for (int off = 1; off < 64; off <<= 1) {
        int y = __shfl_up(x, off);
        if (lane >= off) x += y;
    }
    __shared__ int wsum[16];
    if (lane == 63) wsum[w] = x;
    __syncthreads();
    if (t < 16) {
        int s = wsum[t];
        int xx = s;
        #pragma unroll
        for (int off = 1; off < 16; off <<= 1) {
            int y = __shfl_up(xx, off);
            if (t >= off) xx += y;
        }
        wsum[t] = xx - s;
    }
    __syncthreads();
    int excl = wsum[w] + x - v;
    if (g < N) local[g] = excl;
    if (t == 1023) bsum[blockIdx.x] = excl + v;
}

__global__ __launch_bounds__(256) void scan3(const int* __restrict__ local,
                                             const int* __restrict__ bsum,
                                             int* __restrict__ rowptr,
                                             int N, int E, int NB) {
    __shared__ int sb[64];
    int t = threadIdx.x;
    if (t < 64) {
        int v = (t < NB) ? bsum[t] : 0;
        int x = v;
        #pragma unroll
        for (int off = 1; off < 64; off <<= 1) {
            int y = __shfl_up(x, off);
            if (t >= off) x += y;
        }
        sb[t] = x - v;
    }
    __syncthreads();
    int g = blockIdx.x * 256 + t;
    if (g < N) rowptr[g] = local[g] + sb[g >> 10];
    if (g == 0) rowptr[N] = E;
}

__global__ __launch_bounds__(256) void scatter_plain(const int* __restrict__ src,
                                                     const int* __restrict__ dst,
                                                     const int* __restrict__ rowptr,
                                                     const int* __restrict__ rank,
                                                     int* __restrict__ csr, int E) {
    int e = blockIdx.x * 256 + threadIdx.x;
    if (e < E) {
        int d = dst[e];
        csr[rowptr[d] + rank[e]] = src[e];
    }
}

// ---------------- bf16x3 MFMA GEMM (W2/W3): out = (X @ W) * dinv ----------------

__global__ __launch_bounds__(256) void gemm_w(const unsigned* __restrict__ Xh,
                                              const unsigned* __restrict__ Xl,
                                              const unsigned short* __restrict__ WTh,
                                              const unsigned short* __restrict__ WTl,
                                              const float* __restrict__ dinv,
                                              float* __restrict__ out, int N) {
    __shared__ unsigned short xh[64 * 128];
    __shared__ unsigned short xl[64 * 128];
    __shared__ unsigned short wh[128 * 40];
    __shared__ unsigned short wl[128 * 40];
    int tid = threadIdx.x;
    int lane = tid & 63, wv = tid >> 6;
    int row0 = blockIdx.x * 64;

    #pragma unroll
    for (int i = 0; i < 4; ++i) {
        int id = i * 256 + tid;
        int r = id >> 4, kc = id & 15;
        uint4 vh = make_uint4(0, 0, 0, 0), vl = make_uint4(0, 0, 0, 0);
        if (row0 + r < N) {
            vh = *(const uint4*)&Xh[(size_t)(row0 + r) * 64 + kc * 4];
            vl = *(const uint4*)&Xl[(size_t)(row0 + r) * 64 + kc * 4];
        }
        int off = r * 128 + ((kc * 8) ^ ((r & 7) << 3));
        *(uint4*)&xh[off] = vh;
        *(uint4*)&xl[off] = vl;
    }

    int mstrip = (wv & 1) * 32;
    int nbase = (wv >> 1) * 64;
    f32x4 acc[2][4] = {};

    for (int ks = 0; ks < 4; ++ks) {
        __syncthreads();
        #pragma unroll
        for (int i = 0; i < 2; ++i) {
            int id = i * 256 + tid;        // 0..511
            int n = id >> 2, q = id & 3;
            *(uint4*)&wh[n * 40 + q * 8] =
                *(const uint4*)&WTh[(size_t)n * 128 + ks * 32 + q * 8];
            *(uint4*)&wl[n * 40 + q * 8] =
                *(const uint4*)&WTl[(size_t)n * 128 + ks * 32 + q * 8];
        }
        __syncthreads();

        short8v afh[2], afl[2];
        #pragma unroll
        for (int mt = 0; mt < 2; ++mt) {
            int r = mstrip + mt * 16 + (lane & 15);
            int off = r * 128 + ((ks * 32 + ((lane >> 4) * 8)) ^ ((r & 7) << 3));
            afh[mt] = *(const short8v*)&xh[off];
            afl[mt] = *(const short8v*)&xl[off];
        }
        #pragma unroll
        for (int nt = 0; nt < 4; ++nt) {
            int c = nbase + nt * 16 + (lane & 15);
            int boff = c * 40 + (lane >> 4) * 8;
            short8v bfh = *(const short8v*)&wh[boff];
            short8v bfl = *(const short8v*)&wl[boff];
            #pragma unroll
            for (int mt = 0; mt < 2; ++mt) {
                acc[mt][nt] = __builtin_amdgcn_mfma_f32_16x16x32_bf16(afh[mt], bfh, acc[mt][nt], 0, 0, 0);
                acc[mt][nt] = __builtin_amdgcn_mfma_f32_16x16x32_bf16(afh[mt], bfl, acc[mt][nt], 0, 0, 0);
                acc[mt][nt] = __builtin_amdgcn_mfma_f32_16x16x32_bf16(afl[mt], bfh, acc[mt][nt], 0, 0, 0);
            }
        }
    }

    #pragma unroll
    for (int mt = 0; mt < 2; ++mt) {
        #pragma unroll
        for (int i = 0; i < 4; ++i) {
            int r = row0 + mstrip + mt * 16 + (lane >> 4) * 4 + i;
            if (r < N) {
                float dv = dinv[r];
                #pragma unroll
                for (int nt = 0; nt < 4; ++nt) {
                    int cg = nbase + nt * 16 + (lane & 15);
                    out[(size_t)r * 128 + cg] = acc[mt][nt][i] * dv;
                }
            }
        }
    }
}

// layer 4: X (bf16 hi/lo) @ W4 -> hs4 [N][16] fp32 scaled by dinv
__global__ __launch_bounds__(256) void gemm16(const unsigned* __restrict__ Xh,
                                              const unsigned* __restrict__ Xl,
                                              const float* __restrict__ W,
                                              const float* __restrict__ dinv,
                                              float* __restrict__ out, int N) {
    __shared__ float xs[64][128];
    __shared__ float ws4[128][16];
    int tid = threadIdx.x;
    int row0 = blockIdx.x * 64;

    #pragma unroll
    for (int i = 0; i < 2; ++i)
        ((float4*)ws4)[i * 256 + tid] = ((const float4*)W)[i * 256 + tid];

    #pragma unroll
    for (int i = 0; i < 8; ++i) {
        int id = i * 256 + tid;
        int r = id >> 5, c4 = id & 31;
        float4 v = make_float4(0.f, 0.f, 0.f, 0.f);
        if (row0 + r < N) {
            uint2 hh = *(const uint2*)&Xh[(size_t)(row0 + r) * 64 + c4 * 2];
            uint2 ll = *(const uint2*)&Xl[(size_t)(row0 + r) * 64 + c4 * 2];
            v.x = bf2f(hh.x & 0xffffu) + bf2f(ll.x & 0xffffu);
            v.y = bf2f(hh.x >> 16) + bf2f(ll.x >> 16);
            v.z = bf2f(hh.y & 0xffffu) + bf2f(ll.y & 0xffffu);
            v.w = bf2f(hh.y >> 16) + bf2f(ll.y >> 16);
        }
        *(float4*)&xs[r][c4 * 4] = v;
    }
    __syncthreads();

    int ty = tid >> 4, tx = tid & 15;
    float acc[4] = {};
    #pragma unroll 4
    for (int k = 0; k < 128; ++k) {
        float wvv = ws4[k][tx];
        #pragma unroll
        for (int i = 0; i < 4; ++i)
            acc[i] = fmaf(xs[ty * 4 + i][k], wvv, acc[i]);
    }
    #pragma unroll
    for (int i = 0; i < 4; ++i) {
        int r = row0 + ty * 4 + i;
        if (r < N) out[(size_t)r * 16 + tx] = acc[i] * dinv[r];
    }
}

// ---------------- plain aggregation (layers 2,3) ----------------

template <int ACT>
__global__ __launch_bounds__(256) void agg128(const float* __restrict__ HS,
                                              const int* __restrict__ rp,
                                              const int* __restrict__ csr,
                                              const float* __restrict__ dinv,
                                              const float* __restrict__ b,
                                              unsigned* __restrict__ Xh,
                                              unsigned* __restrict__ Xl, int N) {
    int wid = threadIdx.x >> 6, lane = threadIdx.x & 63;
    int n = blockIdx.x * 4 + wid;
    if (n >= N) return;
    const float2* H2 = (const float2*)HS;
    float2 a0 = H2[(size_t)n * 64 + lane];  // self term
    float2 a1 = make_float2(0.f, 0.f), a2 = a1, a3 = a1;
    float2 a4 = a1, a5 = a1, a6 = a1, a7 = a1;
    int e = rp[n], end = rp[n + 1];
    for (; e + 8 <= end; e += 8) {
        int s0 = csr[e], s1 = csr[e + 1], s2 = csr[e + 2], s3 = csr[e + 3];
        int s4 = csr[e + 4], s5 = csr[e + 5], s6 = csr[e + 6], s7 = csr[e + 7];
        float2 v0 = H2[(size_t)s0 * 64 + lane];
        float2 v1 = H2[(size_t)s1 * 64 + lane];
        float2 v2 = H2[(size_t)s2 * 64 + lane];
        float2 v3 = H2[(size_t)s3 * 64 + lane];
        float2 v4 = H2[(size_t)s4 * 64 + lane];
        float2 v5 = H2[(size_t)s5 * 64 + lane];
        float2 v6 = H2[(size_t)s6 * 64 + lane];
        float2 v7 = H2[(size_t)s7 * 64 + lane];
        a0.x += v0.x; a0.y += v0.y; a1.x += v1.x; a1.y += v1.y;
        a2.x += v2.x; a2.y += v2.y; a3.x += v3.x; a3.y += v3.y;
        a4.x += v4.x; a4.y += v4.y; a5.x += v5.x; a5.y += v5.y;
        a6.x += v6.x; a6.y += v6.y; a7.x += v7.x; a7.y += v7.y;
    }
    if (e + 4 <= end) {
        int s0 = csr[e], s1 = csr[e + 1], s2 = csr[e + 2], s3 = csr[e + 3];
        float2 v0 = H2[(size_t)s0 * 64 + lane];
        float2 v1 = H2[(size_t)s1 * 64 + lane];
        float2 v2 = H2[(size_t)s2 * 64 + lane];
        float2 v3 = H2[(size_t)s3 * 64 + lane];
        a4.x += v0.x; a4.y += v0.y; a5.x += v1.x; a5.y += v1.y;
        a6.x += v2.x; a6.y += v2.y; a7.x += v3.x; a7.y += v3.y;
        e += 4;
    }
    for (; e < end; ++e) {
        int s = csr[e];
        float2 v = H2[(size_t)s * 64 + lane];
        a0.x += v.x; a0.y += v.y;
    }
    float accx = ((a0.x + a1.x) + (a2.x + a3.x)) + ((a4.x + a5.x) + (a6.x + a7.x));
    float accy = ((a0.y + a1.y) + (a2.y + a3.y)) + ((a4.y + a5.y) + (a6.y + a7.y));
    float dv = dinv[n];
    float2 bb = ((const float2*)b)[lane];
    float ox = fmaf(dv, accx, bb.x);
    float oy = fmaf(dv, accy, bb.y);
    if (ACT == 1) { ox = tanhf(ox); oy = tanhf(oy); }
    else if (ACT == 2) {
        ox = ox > 0.f ? ox : 0.01f * ox;
        oy = oy > 0.f ? oy : 0.01f * oy;
    }
    unsigned short h0 = f2bf(ox), h1 = f2bf(oy);
    float l0 = ox - bf2f(h0), l1 = oy - bf2f(h1);
    Xh[(size_t)n * 64 + lane] = (unsigned)h0 | ((unsigned)h1 << 16);
    Xl[(size_t)n * 64 + lane] = (unsigned)f2bf(l0) | ((unsigned)f2bf(l1) << 16);
}

// ---------------- layer-1 aggregation (standalone, deferred dinv) ----------------

__global__ __launch_bounds__(256) void agg_defer(const float* __restrict__ HS,
                                                 const int* __restrict__ rp,
                                                 const int* __restrict__ csr,
                                                 const float* __restrict__ dinv,
                                                 const float* __restrict__ b,
                                                 unsigned* __restrict__ Xh,
                                                 unsigned* __restrict__ Xl, int N) {
    int wid = threadIdx.x >> 6, lane = threadIdx.x & 63;
    int n = blockIdx.x * 4 + wid;
    if (n >= N) return;
    const float2* H2 = (const float2*)HS;
    float2 self = H2[(size_t)n * 64 + lane];
    float2 a0 = make_float2(0.f, 0.f), a1 = a0, a2 = a0, a3 = a0;
    float2 a4 = a0, a5 = a0, a6 = a0, a7 = a0;
    int e = rp[n], end = rp[n + 1];
    for (; e + 8 <= end; e += 8) {
        int s0 = csr[e], s1 = csr[e + 1], s2 = csr[e + 2], s3 = csr[e + 3];
        int s4 = csr[e + 4], s5 = csr[e + 5], s6 = csr[e + 6], s7 = csr[e + 7];
        float2 v0 = H2[(size_t)s0 * 64 + lane];
        float2 v1 = H2[(size_t)s1 * 64 + lane];
        float2 v2 = H2[(size_t)s2 * 64 + lane];
        float2 v3 = H2[(size_t)s3 * 64 + lane];
        float2 v4 = H2[(size_t)s4 * 64 + lane];
        float2 v5 = H2[(size_t)s5 * 64 + lane];
        float2 v6 = H2[(size_t)s6 * 64 + lane];
        float2 v7 = H2[(size_t)s7 * 64 + lane];
        float d0 = dinv[s0], d1 = dinv[s1], d2 = dinv[s2], d3 = dinv[s3];
        float d4 = dinv[s4], d5 = dinv[s5], d6 = dinv[s6], d7 = dinv[s7];
        a0.x = fmaf(v0.x, d0, a0.x); a0.y = fmaf(v0.y, d0, a0.y);
        a1.x = fmaf(v1.x, d1, a1.x); a1.y = fmaf(v1.y, d1, a1.y);
        a2.x = fmaf(v2.x, d2, a2.x); a2.y = fmaf(v2.y, d2, a2.y);
        a3.x = fmaf(v3.x, d3, a3.x); a3.y = fmaf(v3.y, d3, a3.y);
        a4.x = fmaf(v4.x, d4, a4.x); a4.y = fmaf(v4.y, d4, a4.y);
        a5.x = fmaf(v5.x, d5, a5.x); a5.y = fmaf(v5.y, d5, a5.y);
        a6.x = fmaf(v6.x, d6, a6.x); a6.y = fmaf(v6.y, d6, a6.y);
        a7.x = fmaf(v7.x, d7, a7.x); a7.y = fmaf(v7.y, d7, a7.y);
    }
    if (e + 4 <= end) {
        int s0 = csr[e], s1 = csr[e + 1], s2 = csr[e + 2], s3 = csr[e + 3];
        float2 v0 = H2[(size_t)s0 * 64 + lane];
        float2 v1 = H2[(size_t)s1 * 64 + lane];
        float2 v2 = H2[(size_t)s2 * 64 + lane];
        float2 v3 = H2[(size_t)s3 * 64 + lane];
        float d0 = dinv[s0], d1 = dinv[s1], d2 = dinv[s2], d3 = dinv[s3];
        a4.x = fmaf(v0.x, d0, a4.x); a4.y = fmaf(v0.y, d0, a4.y);
        a5.x = fmaf(v1.x, d1, a5.x); a5.y = fmaf(v1.y, d1, a5.y);
        a6.x = fmaf(v2.x, d2, a6.x); a6.y = fmaf(v2.y, d2, a6.y);
        a7.x = fmaf(v3.x, d3, a7.x); a7.y = fmaf(v3.y, d3, a7.y);
        e += 4;
    }
    for (; e < end; ++e) {
        int s = csr[e];
        float2 v = H2[(size_t)s * 64 + lane];
        float d = dinv[s];
        a0.x = fmaf(v.x, d, a0.x); a0.y = fmaf(v.y, d, a0.y);
    }
    float accx = ((a0.x + a1.x) + (a2.x + a3.x)) + ((a4.x + a5.x) + (a6.x + a7.x));
    float accy = ((a0.y + a1.y) + (a2.y + a3.y)) + ((a4.y + a5.y) + (a6.y + a7.y));
    float dv = dinv[n];
    accx = fmaf(dv, self.x, accx);
    accy = fmaf(dv, self.y, accy);
    float2 bb = ((const float2*)b)[lane];
    float ox = fmaf(dv, accx, bb.x);
    float oy = fmaf(dv, accy, bb.y);
    unsigned short h0 = f2bf(ox), h1 = f2bf(oy);
    float l0 = ox - bf2f(h0), l1 = oy - bf2f(h1);
    Xh[(size_t)n * 64 + lane] = (unsigned)h0 | ((unsigned)h1 << 16);
    Xl[(size_t)n * 64 + lane] = (unsigned)f2bf(l0) | ((unsigned)f2bf(l1) << 16);
}

// ---------------- layer-4 aggregation + classifier head ----------------

__global__ __launch_bounds__(256) void final_layer(const float* __restrict__ HS4,
                                                   const int* __restrict__ rp,
                                                   const int* __restrict__ csr,
                                                   const float* __restrict__ dinv,
                                                   const float* __restrict__ b4,
                                                   const float* __restrict__ Wc,
                                                   const float* __restrict__ bc,
                                                   float* __restrict__ out, int N) {
    int wid = threadIdx.x >> 6, lane = threadIdx.x & 63;
    int n = blockIdx.x * 4 + wid;
    if (n >= N) return;
    int f = lane & 15, g = lane >> 4;
    float acc = 0.f;
    int beg = rp[n], end = rp[n + 1];
    for (int e = beg + g; e < end; e += 4)
        acc += HS4[(size_t)csr[e] * 16 + f];
    acc += __shfl_xor(acc, 16);
    acc += __shfl_xor(acc, 32);
    acc += HS4[(size_t)n * 16 + f];
    float t = fmaf(dinv[n], acc, b4[f]);
    t = t > 0.f ? t : 0.01f * t;
    float p = t * Wc[f];
    p += __shfl_xor(p, 1);
    p += __shfl_xor(p, 2);
    p += __shfl_xor(p, 4);
    p += __shfl_xor(p, 8);
    if (lane == 0) {
        float z = p + bc[0];
        out[n] = z > 0.f ? z : expm1f(z);
    }
}

// ---------------- launch ----------------

extern "C" void kernel_launch(void* const* d_in, const int* in_sizes, int n_in,
                              void* d_out, int out_size, void* d_ws, size_t ws_size,
                              hipStream_t stream) {
    const int N = NN, E = NE;
    const float* x  = (const float*)d_in[0];
    const int*   ei = (const int*)d_in[1];
    const float* W1 = (const float*)d_in[2];
    const float* b1 = (const float*)d_in[3];
    const float* W2 = (const float*)d_in[4];
    const float* b2 = (const float*)d_in[5];
    const float* W3 = (const float*)d_in[6];
    const float* b3 = (const float*)d_in[7];
    const float* W4 = (const float*)d_in[8];
    const float* b4 = (const float*)d_in[9];
    const float* Wc = (const float*)d_in[10];
    const float* bc = (const float*)d_in[11];
    float* out = (float*)d_out;
    const int* src = ei;
    const int* dst = ei + E;

    char* p = (char*)d_ws;
    auto carve = [&](size_t bytes) -> char* {
        char* q = p;
        p += (bytes + 255) & ~(size_t)255;
        return q;
    };
    int*            cntP   = (int*)carve((size_t)N * 16 * 4);
    int*            rank   = (int*)carve((size_t)E * 4);
    int*            rowptr = (int*)carve((size_t)(N + 1) * 4);
    float*          dinv   = (float*)carve((size_t)N * 4);
    int*            csr    = (int*)carve((size_t)E * 4);
    int*            locsc  = (int*)carve((size_t)N * 4);
    int*            bsum   = (int*)carve((size_t)64 * 4);
    unsigned short* WTh    = (unsigned short*)carve((size_t)(3 * 16384 + 2048) * 2);
    unsigned short* WTl    = (unsigned short*)carve((size_t)(3 * 16384 + 2048) * 2);
    unsigned*       Xh     = (unsigned*)carve((size_t)N * 64 * 4);
    unsigned*       Xl     = (unsigned*)carve((size_t)N * 64 * 4);
    float*          bufB   = (float*)carve((size_t)N * 128 * 4);
    float*          hs4    = (float*)carve((size_t)N * 16 * 4);

    const int NB = (N + 1023) / 1024;              // 49
    const int gblocks = (N + 63) / 64;             // 782
    const int cblocks = (E + 255) / 256;           // 3125
    const int wblocks = (3 * 16384 + 2048) / 256;  // 200
    const int zblocks = (N * 16 + 255) / 256;      // 3125
    const int ablocks = (N + 3) / 4;               // 12500

    // W pre-split + counter zeroing (independent block ranges)
    wsplit_zero<<<wblocks + zblocks, 256, 0, stream>>>(W1, W2, W3, W4, WTh, WTl, cntP, wblocks);
    // concurrent: layer-1 GEMM (raw h1) + degree count
    mega<<<gblocks + cblocks, 256, 0, stream>>>(x, WTh, WTl, bufB, dst, cntP, rank, N, E, gblocks);
    scan1<<<NB, 1024, 0, stream>>>(cntP, locsc, bsum, dinv, N);
    scan3<<<(N + 255) / 256, 256, 0, stream>>>(locsc, bsum, rowptr, N, E, NB);
    scatter_plain<<<cblocks, 256, 0, stream>>>(src, dst, rowptr, rank, csr, E);

    // layer 1 agg (deferred dinv) -> split
    agg_defer<<<ablocks, 256, 0, stream>>>(bufB, rowptr, csr, dinv, b1, Xh, Xl, N);
    // layer 2
    gemm_w<<<gblocks, 256, 0, stream>>>(Xh, Xl, WTh + 16384, WTl + 16384, dinv, bufB, N);
    agg128<1><<<ablocks, 256, 0, stream>>>(bufB, rowptr, csr, dinv, b2, Xh, Xl, N);
    // layer 3
    gemm_w<<<gblocks, 256, 0, stream>>>(Xh, Xl, WTh + 32768, WTl + 32768, dinv, bufB, N);
    agg128<2><<<ablocks, 256, 0, stream>>>(bufB, rowptr, csr, dinv, b3, Xh, Xl, N);
    // layer 4 + head
    gemm16<<<gblocks, 256, 0, stream>>>(Xh, Xl, W4, dinv, hs4, N);
    final_layer<<<ablocks, 256, 0, stream>>>(hs4, rowptr, csr, dinv, b4, Wc, bc, out, N);
}